// Round 7
// baseline (458.433 us; speedup 1.0000x reference)
//
#include <hip/hip_runtime.h>
#include <hip/hip_bf16.h>

#define NUM_USER 50000
#define N_NODES  80000
#define DIM      64
#define NEG_SLOPE 0.01f

// bucket geometry: 256 rows per bucket, fixed capacity (no count pass)
#define NB 313               // ceil(80000/256)
#define BSHIFT 8
#define RMASK 255
#define CSHIFT 17
#define CMASK 0x1FFFF
#define CAP 10240            // item buckets ~6.8K +- 81 -> ~42 sigma margin

typedef __attribute__((ext_vector_type(8))) short short8;   // 8 bf16 = 4 VGPRs
typedef __attribute__((ext_vector_type(4))) float f32x4;    // MFMA 16x16 accumulator

typedef unsigned short XT;   // state dtype: bf16

__device__ __forceinline__ float leaky(float v) {
    return v > 0.0f ? v : v * NEG_SLOPE;
}

// flags[0]: edge_index is int64 (else int32)
// flags[1]: float inputs are bf16 (else fp32)
__device__ __forceinline__ int load_idx(const void* ei, int is64, long long pos) {
    if (is64) return (int)((const long long*)ei)[pos];
    return ((const int*)ei)[pos];
}
__device__ __forceinline__ float load_f(const void* p, int isbf16, size_t i) {
    if (isbf16) return __bfloat162float(((const __hip_bfloat16*)p)[i]);
    return ((const float*)p)[i];
}

__device__ __forceinline__ unsigned short f2bf(float f) {
    unsigned u = __float_as_uint(f);
    u += 0x7fffu + ((u >> 16) & 1u);   // RNE
    return (unsigned short)(u >> 16);
}

__device__ __forceinline__ void acc8(float* a, uint4 r) {
    a[0] += __uint_as_float(r.x << 16);
    a[1] += __uint_as_float(r.x & 0xffff0000u);
    a[2] += __uint_as_float(r.y << 16);
    a[3] += __uint_as_float(r.y & 0xffff0000u);
    a[4] += __uint_as_float(r.z << 16);
    a[5] += __uint_as_float(r.z & 0xffff0000u);
    a[6] += __uint_as_float(r.w << 16);
    a[7] += __uint_as_float(r.w & 0xffff0000u);
}

// ---------- detect (wave-parallel) + zero bucket cursors ----------
__global__ void detect_kernel(const unsigned int* __restrict__ feat_words,
                              const int* __restrict__ ei_words,
                              int* __restrict__ flags,
                              int* __restrict__ bucketCur) {
    int lane = threadIdx.x & 63;
    for (int i = lane; i < 320; i += 64) bucketCur[i] = 0;
    int orv = 0;
    for (int i = lane * 2 + 1; i < 1024; i += 128) orv |= ei_words[i];
    int hits = 0;
    for (int i = lane; i < 256; i += 64) {
        unsigned e = (feat_words[i] >> 7) & 0xFF;
        hits += (e == 126 || e == 127) ? 1 : 0;
    }
    #pragma unroll
    for (int d = 32; d > 0; d >>= 1) {
        orv  |= __shfl_xor(orv, d, 64);
        hits += __shfl_xor(hits, d, 64);
    }
    if (lane == 0 && blockIdx.x == 0) {
        flags[0] = (orv == 0) ? 1 : 0;
        flags[1] = (hits > 64) ? 1 : 0;
    }
}

// ---------- megafuse: binplace + init_x + W/b pack (three block ranges) ----------
__global__ __launch_bounds__(256) void megafuse_kernel(
        const void* __restrict__ ei, int E, int binBlocks, int initBlocks,
        const int* __restrict__ flags,
        int* __restrict__ bucketCur, unsigned int* __restrict__ recs,
        const void* __restrict__ vp, const void* __restrict__ tp,
        const void* __restrict__ vf, const void* __restrict__ tf,
        XT* __restrict__ xc,
        const void* __restrict__ vW, const void* __restrict__ tW,
        const void* __restrict__ vb, const void* __restrict__ tb,
        unsigned short* __restrict__ Wbf, float* __restrict__ bfp) {
    if ((int)blockIdx.x < binBlocks) {
        // ---- edges -> fixed-cap bucket records (block-aggregated cursors)
        __shared__ int bloc[320];
        __shared__ int bres[320];
        int tid = threadIdx.x;
        for (int i = tid; i < 320; i += 256) bloc[i] = 0;
        __syncthreads();
        int is64 = flags[0];
        long long base = (long long)blockIdx.x * 2048;
        int bb[8], cc[8], lp[8], rl[8];
        #pragma unroll
        for (int it = 0; it < 8; ++it) {
            bb[it] = -1;
            long long e = base + it * 256 + tid;
            if (e < E) {
                int r = load_idx(ei, is64, e);
                int c = load_idx(ei, is64, (long long)E + e);
                if ((unsigned)r < N_NODES && (unsigned)c < N_NODES) {
                    int b = r >> BSHIFT;
                    bb[it] = b;
                    cc[it] = c;
                    rl[it] = r & RMASK;
                    lp[it] = atomicAdd(&bloc[b], 1);
                }
            }
        }
        __syncthreads();
        for (int i = tid; i < NB; i += 256) {
            int v = bloc[i];
            bres[i] = v ? atomicAdd(&bucketCur[i], v) : 0;
        }
        __syncthreads();
        #pragma unroll
        for (int it = 0; it < 8; ++it) {
            if (bb[it] >= 0) {
                int pos = bres[bb[it]] + lp[it];
                if (pos < CAP)
                    recs[(size_t)bb[it] * CAP + pos] =
                        ((unsigned)rl[it] << CSHIFT) | (unsigned)cc[it];
            }
        }
    } else if ((int)blockIdx.x < binBlocks + initBlocks) {
        // ---- init_x: L2-normalize [pref|feat] rows -> bf16 state
        int n = (blockIdx.x - binBlocks) * 4 + (threadIdx.x >> 6);
        if (n >= N_NODES) return;
        int lane = threadIdx.x & 63;
        int isb = flags[1];
        float a, b;
        if (n < NUM_USER) {
            a = load_f(vp, isb, (size_t)n * DIM + lane);
            b = load_f(tp, isb, (size_t)n * DIM + lane);
        } else {
            a = load_f(vf, isb, (size_t)(n - NUM_USER) * DIM + lane);
            b = load_f(tf, isb, (size_t)(n - NUM_USER) * DIM + lane);
        }
        float sa = a * a, sb = b * b;
        #pragma unroll
        for (int d = 32; d > 0; d >>= 1) {
            sa += __shfl_xor(sa, d, 64);
            sb += __shfl_xor(sb, d, 64);
        }
        float ra = 1.0f / fmaxf(sqrtf(sa), 1e-12f);
        float rb = 1.0f / fmaxf(sqrtf(sb), 1e-12f);
        xc[(size_t)n * 128 + lane]      = f2bf(a * ra);
        xc[(size_t)n * 128 + 64 + lane] = f2bf(b * rb);
    } else {
        // ---- W/b pack
        int isb = flags[1];
        int j = (blockIdx.x - binBlocks - initBlocks) * 256 + threadIdx.x;
        if (j < 2 * 24576) {
            int tw = j / 24576, r = j % 24576;
            Wbf[j] = f2bf(load_f(tw ? tW : vW, isb, r));
        } else if (j < 2 * 24576 + 2 * 384) {
            int i2 = j - 2 * 24576;
            int tw = i2 / 384, r = i2 % 384;
            bfp[i2] = f2bf(0.0f), bfp[i2] = load_f(tw ? tb : vb, isb, r);
        }
    }
}

// ---------- bin2csr: one block per bucket, 1024 threads ----------
__global__ __launch_bounds__(1024) void bin2csr_kernel(
        const unsigned int* __restrict__ recs,
        const int* __restrict__ bucketCur,
        int* __restrict__ cnt, int* __restrict__ cur,
        int* __restrict__ csr) {
    __shared__ int rcnt[256];
    __shared__ int sc[256];
    __shared__ int lcur[256];
    int b = blockIdx.x;
    int t = threadIdx.x;
    int base = b * CAP;
    int count = bucketCur[b];
    if (count > CAP) count = CAP;

    if (t < 256) { rcnt[t] = 0; lcur[t] = 0; }
    __syncthreads();
    for (int i = t; i < count; i += 1024) {
        unsigned rec = recs[(size_t)base + i];
        atomicAdd(&rcnt[rec >> CSHIFT], 1);
    }
    __syncthreads();
    int v = (t < 256) ? rcnt[t] : 0;
    if (t < 256) sc[t] = v;
    __syncthreads();
    for (int d = 1; d < 256; d <<= 1) {
        int x = 0;
        if (t < 256) { x = sc[t]; if (t >= d) x += sc[t - d]; }
        __syncthreads();
        if (t < 256) sc[t] = x;
        __syncthreads();
    }
    if (t < 256) {
        int row = (b << BSHIFT) + t;
        if (row < N_NODES) {
            cnt[row] = v;
            cur[row] = base + sc[t];   // row end; gather recovers start = cur - cnt
        }
    }
    __syncthreads();
    for (int i = t; i < count; i += 1024) {
        unsigned rec = recs[(size_t)base + i];
        int rloc = rec >> CSHIFT;
        int c = rec & CMASK;
        int pos = base + (sc[rloc] - rcnt[rloc]) + atomicAdd(&lcur[rloc], 1);
        csr[pos] = c;
    }
}

// ---------- fused layer: per-wave gather (proven shape) -> LDS -> dense ----------
// Each wave owns 16 nodes: gathers them serially with the 8-group/unroll-2
// loop (no degree divergence), stages bf16 means in a wave-private LDS tile
// (row stride 136 shorts = 272B -> 2 lanes/bank, conflict-free), then runs
// the both-towers dense reading A-fragments from LDS. Kills the agg global
// round-trip + one launch per layer; gather of late blocks overlaps dense of
// early blocks. Ping-pong xin->xout (gather reads arbitrary rows). last=1
// writes (x_v+x_t)/2 straight to out.
__global__ __launch_bounds__(256) void layer_fused_kernel(
        const XT* __restrict__ xin, XT* __restrict__ xout,
        void* __restrict__ out, int last,
        const void* __restrict__ id_emb,
        const unsigned short* __restrict__ Wbf, const float* __restrict__ bfp,
        const int* __restrict__ cnt, const int* __restrict__ cur,
        const int* __restrict__ csr,
        int layer, const int* __restrict__ flags) {
    __shared__ unsigned short aggs[4][16 * 136];   // 17408 B
    __shared__ unsigned short hts[4][16 * 72];     //  9216 B
    int wave = threadIdx.x >> 6, lane = threadIdx.x & 63;
    int quad = lane >> 4, l16 = lane & 15;
    int isb = flags[1];
    int n0 = (blockIdx.x * 4 + wave) * 16;
    unsigned short* agg = aggs[wave];
    unsigned short* ht  = hts[wave];

    // ---- gather phase: 16 nodes serial, 8 streams per wave
    {
        int g8 = lane >> 3;      // 0..7
        int s  = lane & 7;       // 0..7
        int gg = g8 >> 1;        // 0..3: neighbor stride class
        int h  = g8 & 1;         // 0/1: row half
        const XT* xh = xin + h * 64;

        for (int k = 0; k < 16; ++k) {
            int node = n0 + k;
            int d = cnt[node];
            int base = cur[node] - d;
            const int* nb = csr + base;

            float acc[8];
            #pragma unroll
            for (int f = 0; f < 8; ++f) acc[f] = 0.f;

            int jj = gg;
            for (; jj + 4 < d; jj += 8) {
                int c0 = nb[jj];
                int c1 = nb[jj + 4];
                uint4 r0 = ((const uint4*)(xh + (size_t)c0 * 128))[s];
                uint4 r1 = ((const uint4*)(xh + (size_t)c1 * 128))[s];
                acc8(acc, r0);
                acc8(acc, r1);
            }
            if (jj < d) {
                uint4 r0 = ((const uint4*)(xh + (size_t)nb[jj] * 128))[s];
                acc8(acc, r0);
            }

            #pragma unroll
            for (int dd = 16; dd < 64; dd <<= 1) {
                #pragma unroll
                for (int f = 0; f < 8; ++f) acc[f] += __shfl_xor(acc[f], dd, 64);
            }

            float invd = (d > 0) ? 1.0f / (float)d : 0.0f;
            if (g8 < 2) {   // gg == 0 lanes; h selects the half
                uint4 w;
                w.x = (unsigned)f2bf(acc[0] * invd) | ((unsigned)f2bf(acc[1] * invd) << 16);
                w.y = (unsigned)f2bf(acc[2] * invd) | ((unsigned)f2bf(acc[3] * invd) << 16);
                w.z = (unsigned)f2bf(acc[4] * invd) | ((unsigned)f2bf(acc[5] * invd) << 16);
                w.w = (unsigned)f2bf(acc[6] * invd) | ((unsigned)f2bf(acc[7] * invd) << 16);
                *(uint4*)(agg + k * 136 + h * 64 + s * 8) = w;
            }
        }
    }
    // wave-private LDS, in-order per wave -> no barrier

    // ---- dense phase: both towers; A-fragments for M0 come from LDS
    float res0[16];   // tower-0 results, used only when last

    #pragma unroll
    for (int tw = 0; tw < 2; ++tw) {
        int toff = tw * 64;
        const unsigned short* Wm = Wbf + (size_t)((tw * 2 + layer) * 3) * 4096;
        const float* bb = bfp + (tw * 2 + layer) * 192;
        size_t arow = (size_t)(n0 + l16) * 128 + toff + quad * 8;

        short8 a0, a1;
        f32x4 accP[4];

        // M1: P = leaky(x @ W1^T + b1), in registers
        a0 = *(const short8*)(xin + arow);
        a1 = *(const short8*)(xin + arow + 32);
        #pragma unroll
        for (int t = 0; t < 4; ++t) {
            f32x4 c = {0.f, 0.f, 0.f, 0.f};
            short8 b0 = *(const short8*)(Wm + 4096 + (16 * t + l16) * 64 + quad * 8);
            short8 b1 = *(const short8*)(Wm + 4096 + (16 * t + l16) * 64 + 32 + quad * 8);
            c = __builtin_amdgcn_mfma_f32_16x16x32_bf16(a0, b0, c, 0, 0, 0);
            c = __builtin_amdgcn_mfma_f32_16x16x32_bf16(a1, b1, c, 0, 0, 0);
            float bias = bb[64 + 16 * t + l16];
            #pragma unroll
            for (int r = 0; r < 4; ++r) accP[t][r] = leaky(c[r] + bias);
        }

        // M0: h = leaky(agg @ W0^T + b0) -> LDS ht (C-layout -> A-layout)
        a0 = *(const short8*)(agg + l16 * 136 + toff + quad * 8);
        a1 = *(const short8*)(agg + l16 * 136 + toff + 32 + quad * 8);
        #pragma unroll
        for (int t = 0; t < 4; ++t) {
            f32x4 c = {0.f, 0.f, 0.f, 0.f};
            short8 b0 = *(const short8*)(Wm + (16 * t + l16) * 64 + quad * 8);
            short8 b1 = *(const short8*)(Wm + (16 * t + l16) * 64 + 32 + quad * 8);
            c = __builtin_amdgcn_mfma_f32_16x16x32_bf16(a0, b0, c, 0, 0, 0);
            c = __builtin_amdgcn_mfma_f32_16x16x32_bf16(a1, b1, c, 0, 0, 0);
            float bias = bb[16 * t + l16];
            #pragma unroll
            for (int r = 0; r < 4; ++r)
                ht[(quad * 4 + r) * 72 + 16 * t + l16] = f2bf(leaky(c[r] + bias));
        }

        // M2: x = leaky(h @ W2^T + b2 + P + id)
        a0 = *(const short8*)(ht + l16 * 72 + quad * 8);
        a1 = *(const short8*)(ht + l16 * 72 + 32 + quad * 8);
        #pragma unroll
        for (int t = 0; t < 4; ++t) {
            f32x4 c = {0.f, 0.f, 0.f, 0.f};
            short8 b0 = *(const short8*)(Wm + 2 * 4096 + (16 * t + l16) * 64 + quad * 8);
            short8 b1 = *(const short8*)(Wm + 2 * 4096 + (16 * t + l16) * 64 + 32 + quad * 8);
            c = __builtin_amdgcn_mfma_f32_16x16x32_bf16(a0, b0, c, 0, 0, 0);
            c = __builtin_amdgcn_mfma_f32_16x16x32_bf16(a1, b1, c, 0, 0, 0);
            float bias = bb[128 + 16 * t + l16];
            #pragma unroll
            for (int r = 0; r < 4; ++r) {
                int node2 = n0 + quad * 4 + r;
                int j = 16 * t + l16;
                float idv = load_f(id_emb, isb, (size_t)node2 * 64 + j);
                float v = leaky(c[r] + bias + accP[t][r] + idv);
                if (!last) {
                    xout[(size_t)node2 * 128 + toff + j] = f2bf(v);
                } else if (tw == 0) {
                    res0[t * 4 + r] = v;
                } else {
                    float avg = (res0[t * 4 + r] + v) * 0.5f;
                    if (isb) ((unsigned short*)out)[(size_t)node2 * 64 + j] = f2bf(avg);
                    else     ((float*)out)[(size_t)node2 * 64 + j] = avg;
                }
            }
        }
    }
}

extern "C" void kernel_launch(void* const* d_in, const int* in_sizes, int n_in,
                              void* d_out, int out_size, void* d_ws, size_t ws_size,
                              hipStream_t stream) {
    const void* v_feat = d_in[0];
    const void* t_feat = d_in[1];
    const void* id_emb = d_in[2];
    const void* v_pref = d_in[3];
    const void* t_pref = d_in[4];
    const void* v_W    = d_in[5];
    const void* v_b    = d_in[6];
    const void* t_W    = d_in[7];
    const void* t_b    = d_in[8];
    const void* ei     = d_in[9];

    const int E = in_sizes[9] / 2;   // 1,600,000
    char* ws = (char*)d_ws;

    size_t o = 0;
    int*            flags     = (int*)(ws + o);            o += 16;
    int*            cnt       = (int*)(ws + o);            o += 320000;
    int*            cur       = (int*)(ws + o);            o += 320000;
    int*            bucketCur = (int*)(ws + o);            o += 320 * 4;
    unsigned short* Wbf       = (unsigned short*)(ws + o); o += 2 * 24576 * 2;
    float*          bfp       = (float*)(ws + o);          o += 2 * 384 * 4;
    XT* xcA = (XT*)(ws + o); o += (size_t)N_NODES * 128 * sizeof(XT);
    XT* xcB = (XT*)(ws + o); o += (size_t)N_NODES * 128 * sizeof(XT);
    unsigned int* recs = (unsigned int*)(ws + o); o += (size_t)NB * CAP * 4;
    int* csr = (int*)(ws + o);                    // padded: NB*CAP*4 = 12.8 MB

    detect_kernel<<<dim3(1), dim3(64), 0, stream>>>(
        (const unsigned int*)v_feat, (const int*)ei, flags, bucketCur);

    // fused binplace + init_x + W/b pack
    const int binBlocks  = (E + 2047) / 2048;         // 782
    const int initBlocks = (N_NODES + 3) / 4;         // 20000
    const int packBlocks = (2 * 24576 + 2 * 384 + 255) / 256;
    megafuse_kernel<<<dim3(binBlocks + initBlocks + packBlocks), dim3(256), 0, stream>>>(
        ei, E, binBlocks, initBlocks, flags, bucketCur, recs,
        v_pref, t_pref, v_feat, t_feat, xcA,
        v_W, t_W, v_b, t_b, Wbf, bfp);

    // buckets -> padded CSR + per-row cnt/cur
    bin2csr_kernel<<<dim3(NB), dim3(1024), 0, stream>>>(recs, bucketCur, cnt, cur, csr);

    const int layerBlocks = N_NODES / (16 * 4);       // 1250, exact

    // layer 0: xcA -> xcB ; layer 1: xcB -> out (averaged)
    layer_fused_kernel<<<dim3(layerBlocks), dim3(256), 0, stream>>>(
        xcA, xcB, d_out, 0, id_emb, Wbf, bfp, cnt, cur, csr, 0, flags);
    layer_fused_kernel<<<dim3(layerBlocks), dim3(256), 0, stream>>>(
        xcB, xcA, d_out, 1, id_emb, Wbf, bfp, cnt, cur, csr, 1, flags);
}

// Round 8
// 381.256 us; speedup vs baseline: 1.2024x; 1.2024x over previous
//
#include <hip/hip_runtime.h>
#include <hip/hip_bf16.h>

#define NUM_USER 50000
#define N_NODES  80000
#define DIM      64
#define NEG_SLOPE 0.01f

// bucket geometry: 256 rows per bucket, fixed capacity (no count pass)
#define NB 313               // ceil(80000/256)
#define BSHIFT 8
#define RMASK 255
#define CSHIFT 17
#define CMASK 0x1FFFF
#define CAP 10240            // item buckets ~6.8K +- 81 -> ~42 sigma margin

typedef __attribute__((ext_vector_type(8))) short short8;   // 8 bf16 = 4 VGPRs
typedef __attribute__((ext_vector_type(4))) float f32x4;    // MFMA 16x16 accumulator

typedef unsigned short XT;   // state dtype: bf16

__device__ __forceinline__ float leaky(float v) {
    return v > 0.0f ? v : v * NEG_SLOPE;
}

// flags[0]: edge_index is int64 (else int32)
// flags[1]: float inputs are bf16 (else fp32)
__device__ __forceinline__ int load_idx(const void* ei, int is64, long long pos) {
    if (is64) return (int)((const long long*)ei)[pos];
    return ((const int*)ei)[pos];
}
__device__ __forceinline__ float load_f(const void* p, int isbf16, size_t i) {
    if (isbf16) return __bfloat162float(((const __hip_bfloat16*)p)[i]);
    return ((const float*)p)[i];
}

__device__ __forceinline__ unsigned short f2bf(float f) {
    unsigned u = __float_as_uint(f);
    u += 0x7fffu + ((u >> 16) & 1u);   // RNE
    return (unsigned short)(u >> 16);
}
__device__ __forceinline__ float bf2f(unsigned short v) {
    return __uint_as_float(((unsigned)v) << 16);
}

__device__ __forceinline__ void acc8(float* a, uint4 r) {
    a[0] += __uint_as_float(r.x << 16);
    a[1] += __uint_as_float(r.x & 0xffff0000u);
    a[2] += __uint_as_float(r.y << 16);
    a[3] += __uint_as_float(r.y & 0xffff0000u);
    a[4] += __uint_as_float(r.z << 16);
    a[5] += __uint_as_float(r.z & 0xffff0000u);
    a[6] += __uint_as_float(r.w << 16);
    a[7] += __uint_as_float(r.w & 0xffff0000u);
}

// ---------- detect (wave-parallel) + zero bucket cursors ----------
__global__ void detect_kernel(const unsigned int* __restrict__ feat_words,
                              const int* __restrict__ ei_words,
                              int* __restrict__ flags,
                              int* __restrict__ bucketCur) {
    int lane = threadIdx.x & 63;
    for (int i = lane; i < 320; i += 64) bucketCur[i] = 0;
    int orv = 0;
    for (int i = lane * 2 + 1; i < 1024; i += 128) orv |= ei_words[i];
    int hits = 0;
    for (int i = lane; i < 256; i += 64) {
        unsigned e = (feat_words[i] >> 7) & 0xFF;
        hits += (e == 126 || e == 127) ? 1 : 0;
    }
    #pragma unroll
    for (int d = 32; d > 0; d >>= 1) {
        orv  |= __shfl_xor(orv, d, 64);
        hits += __shfl_xor(hits, d, 64);
    }
    if (lane == 0 && blockIdx.x == 0) {
        flags[0] = (orv == 0) ? 1 : 0;
        flags[1] = (hits > 64) ? 1 : 0;
    }
}

// ---------- binplace: edges -> fixed-cap bucket records ----------
__global__ __launch_bounds__(256) void binplace_kernel(
        const void* __restrict__ ei, int E,
        const int* __restrict__ flags,
        int* __restrict__ bucketCur, unsigned int* __restrict__ recs) {
    __shared__ int bloc[320];
    __shared__ int bres[320];
    int tid = threadIdx.x;
    for (int i = tid; i < 320; i += 256) bloc[i] = 0;
    __syncthreads();
    int is64 = flags[0];
    long long base = (long long)blockIdx.x * 2048;
    int bb[8], cc[8], lp[8], rl[8];
    #pragma unroll
    for (int it = 0; it < 8; ++it) {
        bb[it] = -1;
        long long e = base + it * 256 + tid;
        if (e < E) {
            int r = load_idx(ei, is64, e);
            int c = load_idx(ei, is64, (long long)E + e);
            if ((unsigned)r < N_NODES && (unsigned)c < N_NODES) {
                int b = r >> BSHIFT;
                bb[it] = b;
                cc[it] = c;
                rl[it] = r & RMASK;
                lp[it] = atomicAdd(&bloc[b], 1);
            }
        }
    }
    __syncthreads();
    for (int i = tid; i < NB; i += 256) {
        int v = bloc[i];
        bres[i] = v ? atomicAdd(&bucketCur[i], v) : 0;
    }
    __syncthreads();
    #pragma unroll
    for (int it = 0; it < 8; ++it) {
        if (bb[it] >= 0) {
            int pos = bres[bb[it]] + lp[it];
            if (pos < CAP)
                recs[(size_t)bb[it] * CAP + pos] =
                    ((unsigned)rl[it] << CSHIFT) | (unsigned)cc[it];
        }
    }
}

// ---------- prep2: bin2csr (first) + init_x + W/b/id pack, fused ----------
// bin2csr's 313 low-parallelism blocks overlap with the 10000 init blocks
// and the pack blocks instead of running alone after everything else.
__global__ __launch_bounds__(512) void prep2_kernel(
        const unsigned int* __restrict__ recs, const int* __restrict__ bucketCur,
        int* __restrict__ cnt, int* __restrict__ cur, int* __restrict__ csr,
        int initBlocks, const int* __restrict__ flags,
        const void* __restrict__ vp, const void* __restrict__ tp,
        const void* __restrict__ vf, const void* __restrict__ tf,
        XT* __restrict__ xc,
        const void* __restrict__ vW, const void* __restrict__ tW,
        const void* __restrict__ vb, const void* __restrict__ tb,
        unsigned short* __restrict__ Wbf, float* __restrict__ bfp,
        const void* __restrict__ id_emb, unsigned short* __restrict__ idbf,
        int useIdbf) {
    int bx = blockIdx.x;
    if (bx < NB) {
        // ---- bin2csr: one block per bucket (padded layout, base = b*CAP)
        __shared__ int rcnt[256];
        __shared__ int sc[256];
        __shared__ int lcur[256];
        int b = bx;
        int t = threadIdx.x;
        int base = b * CAP;
        int count = bucketCur[b];
        if (count > CAP) count = CAP;

        if (t < 256) { rcnt[t] = 0; lcur[t] = 0; }
        __syncthreads();
        for (int i = t; i < count; i += 512) {
            unsigned rec = recs[(size_t)base + i];
            atomicAdd(&rcnt[rec >> CSHIFT], 1);
        }
        __syncthreads();
        int v = (t < 256) ? rcnt[t] : 0;
        if (t < 256) sc[t] = v;
        __syncthreads();
        for (int d = 1; d < 256; d <<= 1) {
            int x = 0;
            if (t < 256) { x = sc[t]; if (t >= d) x += sc[t - d]; }
            __syncthreads();
            if (t < 256) sc[t] = x;
            __syncthreads();
        }
        if (t < 256) {
            int row = (b << BSHIFT) + t;
            if (row < N_NODES) {
                cnt[row] = v;
                cur[row] = base + sc[t];   // row end; gather: start = cur - cnt
            }
        }
        __syncthreads();
        for (int i = t; i < count; i += 512) {
            unsigned rec = recs[(size_t)base + i];
            int rloc = rec >> CSHIFT;
            int c = rec & CMASK;
            int pos = base + (sc[rloc] - rcnt[rloc]) + atomicAdd(&lcur[rloc], 1);
            csr[pos] = c;
        }
    } else if (bx < NB + initBlocks) {
        // ---- init_x: L2-normalize [pref|feat] rows -> bf16 state (8 nodes/blk)
        int n = (bx - NB) * 8 + (threadIdx.x >> 6);
        if (n >= N_NODES) return;
        int lane = threadIdx.x & 63;
        int isb = flags[1];
        float a, b;
        if (n < NUM_USER) {
            a = load_f(vp, isb, (size_t)n * DIM + lane);
            b = load_f(tp, isb, (size_t)n * DIM + lane);
        } else {
            a = load_f(vf, isb, (size_t)(n - NUM_USER) * DIM + lane);
            b = load_f(tf, isb, (size_t)(n - NUM_USER) * DIM + lane);
        }
        float sa = a * a, sb = b * b;
        #pragma unroll
        for (int d = 32; d > 0; d >>= 1) {
            sa += __shfl_xor(sa, d, 64);
            sb += __shfl_xor(sb, d, 64);
        }
        float ra = 1.0f / fmaxf(sqrtf(sa), 1e-12f);
        float rb = 1.0f / fmaxf(sqrtf(sb), 1e-12f);
        xc[(size_t)n * 128 + lane]      = f2bf(a * ra);
        xc[(size_t)n * 128 + 64 + lane] = f2bf(b * rb);
    } else {
        // ---- pack: W -> bf16, b -> f32, id_emb -> bf16 (optional)
        int isb = flags[1];
        int j = (bx - NB - initBlocks) * 512 + threadIdx.x;
        if (j < 2 * 24576) {
            int tw = j / 24576, r = j % 24576;
            Wbf[j] = f2bf(load_f(tw ? tW : vW, isb, r));
        } else if (j < 2 * 24576 + 2 * 384) {
            int i2 = j - 2 * 24576;
            int tw = i2 / 384, r = i2 % 384;
            bfp[i2] = load_f(tw ? tb : vb, isb, r);
        } else if (useIdbf) {
            int k = j - (2 * 24576 + 2 * 384);
            if (k < N_NODES * DIM)
                idbf[k] = f2bf(load_f(id_emb, isb, (size_t)k));
        }
    }
}

// ---------- gather: agg[n] = mean over CSR neighbors (proven R3/R6 shape) ----------
// 8 streams/wave: 8 lanes cover a 128B half-row (uint4/lane); group g8 = gg*2+h
// handles neighbors jj = gg (mod 4), half h; unroll-2 per stream.
__global__ __launch_bounds__(512) void gather_kernel(
        const XT* __restrict__ xc, XT* __restrict__ agg,
        const int* __restrict__ cnt, const int* __restrict__ cur,
        const int* __restrict__ csr) {
    int n = blockIdx.x * 8 + (threadIdx.x >> 6);
    if (n >= N_NODES) return;
    int lane = threadIdx.x & 63;
    int g8 = lane >> 3;      // 0..7
    int s  = lane & 7;       // 0..7
    int gg = g8 >> 1;        // 0..3: neighbor stride class
    int h  = g8 & 1;         // 0/1: row half

    int d = cnt[n];
    int base = cur[n] - d;   // row start in padded CSR
    const int* nb = csr + base;
    const XT* xh = xc + h * 64;

    float acc[8];
    #pragma unroll
    for (int f = 0; f < 8; ++f) acc[f] = 0.f;

    int jj = gg;
    for (; jj + 4 < d; jj += 8) {
        int c0 = nb[jj];
        int c1 = nb[jj + 4];
        uint4 r0 = ((const uint4*)(xh + (size_t)c0 * 128))[s];
        uint4 r1 = ((const uint4*)(xh + (size_t)c1 * 128))[s];
        acc8(acc, r0);
        acc8(acc, r1);
    }
    if (jj < d) {
        int c0 = nb[jj];
        uint4 r0 = ((const uint4*)(xh + (size_t)c0 * 128))[s];
        acc8(acc, r0);
    }

    // reduce across gg (lanes differing in bits 4 and 5; same h,s)
    #pragma unroll
    for (int dd = 16; dd < 64; dd <<= 1) {
        #pragma unroll
        for (int f = 0; f < 8; ++f) acc[f] += __shfl_xor(acc[f], dd, 64);
    }

    float invd = (d > 0) ? 1.0f / (float)d : 0.0f;
    if (g8 < 2) {   // gg == 0 lanes; h = g8 selects the half to write
        uint4 w;
        w.x = (unsigned)f2bf(acc[0] * invd) | ((unsigned)f2bf(acc[1] * invd) << 16);
        w.y = (unsigned)f2bf(acc[2] * invd) | ((unsigned)f2bf(acc[3] * invd) << 16);
        w.z = (unsigned)f2bf(acc[4] * invd) | ((unsigned)f2bf(acc[5] * invd) << 16);
        w.w = (unsigned)f2bf(acc[6] * invd) | ((unsigned)f2bf(acc[7] * invd) << 16);
        ((uint4*)(agg + (size_t)n * 128 + h * 64))[s] = w;
    }
}

// ---------- dense via MFMA 16x16x32 bf16, both towers per block (R6) ----------
// id loaded ONCE (shared by towers), bf16-packed if idbf != null. In-place xc
// update is safe: each block reads only its own 16-node rows before writes.
// last=1 writes (x_v+x_t)/2 straight to out.
__global__ __launch_bounds__(256) void dense_mfma_kernel(
        XT* __restrict__ xc, const XT* __restrict__ agg,
        void* __restrict__ out, int last,
        const void* __restrict__ id_emb, const unsigned short* __restrict__ idbf,
        const unsigned short* __restrict__ Wbf, const float* __restrict__ bfp,
        int layer, const int* __restrict__ flags) {
    __shared__ unsigned short hts[4][16 * 72];
    int wave = threadIdx.x >> 6, lane = threadIdx.x & 63;
    int quad = lane >> 4, l16 = lane & 15;
    int isb = flags[1];
    int n0 = (blockIdx.x * 4 + wave) * 16;
    unsigned short* ht = hts[wave];

    float xres[2][16];
    float idv[16];

    #pragma unroll
    for (int tw = 0; tw < 2; ++tw) {
        int toff = tw * 64;
        const unsigned short* Wm = Wbf + (size_t)((tw * 2 + layer) * 3) * 4096;
        const float* bb = bfp + (tw * 2 + layer) * 192;
        size_t arow = (size_t)(n0 + l16) * 128 + toff + quad * 8;

        short8 a0, a1;
        f32x4 accP[4];

        // M1: P = leaky(x @ W1^T + b1), in registers
        a0 = *(const short8*)(xc + arow);
        a1 = *(const short8*)(xc + arow + 32);
        #pragma unroll
        for (int t = 0; t < 4; ++t) {
            f32x4 c = {0.f, 0.f, 0.f, 0.f};
            short8 b0 = *(const short8*)(Wm + 4096 + (16 * t + l16) * 64 + quad * 8);
            short8 b1 = *(const short8*)(Wm + 4096 + (16 * t + l16) * 64 + 32 + quad * 8);
            c = __builtin_amdgcn_mfma_f32_16x16x32_bf16(a0, b0, c, 0, 0, 0);
            c = __builtin_amdgcn_mfma_f32_16x16x32_bf16(a1, b1, c, 0, 0, 0);
            float bias = bb[64 + 16 * t + l16];
            #pragma unroll
            for (int r = 0; r < 4; ++r) accP[t][r] = leaky(c[r] + bias);
        }

        // M0: h = leaky(agg @ W0^T + b0) -> LDS (C-layout -> A-layout)
        a0 = *(const short8*)(agg + arow);
        a1 = *(const short8*)(agg + arow + 32);
        #pragma unroll
        for (int t = 0; t < 4; ++t) {
            f32x4 c = {0.f, 0.f, 0.f, 0.f};
            short8 b0 = *(const short8*)(Wm + (16 * t + l16) * 64 + quad * 8);
            short8 b1 = *(const short8*)(Wm + (16 * t + l16) * 64 + 32 + quad * 8);
            c = __builtin_amdgcn_mfma_f32_16x16x32_bf16(a0, b0, c, 0, 0, 0);
            c = __builtin_amdgcn_mfma_f32_16x16x32_bf16(a1, b1, c, 0, 0, 0);
            float bias = bb[16 * t + l16];
            #pragma unroll
            for (int r = 0; r < 4; ++r)
                ht[(quad * 4 + r) * 72 + 16 * t + l16] = f2bf(leaky(c[r] + bias));
        }
        // wave-private LDS, in-order per wave -> no barrier

        // M2: x = leaky(h @ W2^T + b2 + P + id)
        a0 = *(const short8*)(ht + l16 * 72 + quad * 8);
        a1 = *(const short8*)(ht + l16 * 72 + 32 + quad * 8);
        #pragma unroll
        for (int t = 0; t < 4; ++t) {
            f32x4 c = {0.f, 0.f, 0.f, 0.f};
            short8 b0 = *(const short8*)(Wm + 2 * 4096 + (16 * t + l16) * 64 + quad * 8);
            short8 b1 = *(const short8*)(Wm + 2 * 4096 + (16 * t + l16) * 64 + 32 + quad * 8);
            c = __builtin_amdgcn_mfma_f32_16x16x32_bf16(a0, b0, c, 0, 0, 0);
            c = __builtin_amdgcn_mfma_f32_16x16x32_bf16(a1, b1, c, 0, 0, 0);
            float bias = bb[128 + 16 * t + l16];
            #pragma unroll
            for (int r = 0; r < 4; ++r) {
                int node2 = n0 + quad * 4 + r;
                int j = 16 * t + l16;
                if (tw == 0)
                    idv[t * 4 + r] = idbf ? bf2f(idbf[(size_t)node2 * 64 + j])
                                          : load_f(id_emb, isb, (size_t)node2 * 64 + j);
                xres[tw][t * 4 + r] = leaky(c[r] + bias + accP[t][r] + idv[t * 4 + r]);
            }
        }
    }

    if (!last) {
        #pragma unroll
        for (int tw = 0; tw < 2; ++tw) {
            #pragma unroll
            for (int t = 0; t < 4; ++t) {
                #pragma unroll
                for (int r = 0; r < 4; ++r) {
                    int node2 = n0 + quad * 4 + r;
                    int j = 16 * t + l16;
                    xc[(size_t)node2 * 128 + tw * 64 + j] = f2bf(xres[tw][t * 4 + r]);
                }
            }
        }
    } else {
        #pragma unroll
        for (int t = 0; t < 4; ++t) {
            #pragma unroll
            for (int r = 0; r < 4; ++r) {
                int node2 = n0 + quad * 4 + r;
                int j = 16 * t + l16;
                float avg = (xres[0][t * 4 + r] + xres[1][t * 4 + r]) * 0.5f;
                if (isb) ((unsigned short*)out)[(size_t)node2 * 64 + j] = f2bf(avg);
                else     ((float*)out)[(size_t)node2 * 64 + j] = avg;
            }
        }
    }
}

extern "C" void kernel_launch(void* const* d_in, const int* in_sizes, int n_in,
                              void* d_out, int out_size, void* d_ws, size_t ws_size,
                              hipStream_t stream) {
    const void* v_feat = d_in[0];
    const void* t_feat = d_in[1];
    const void* id_emb = d_in[2];
    const void* v_pref = d_in[3];
    const void* t_pref = d_in[4];
    const void* v_W    = d_in[5];
    const void* v_b    = d_in[6];
    const void* t_W    = d_in[7];
    const void* t_b    = d_in[8];
    const void* ei     = d_in[9];

    const int E = in_sizes[9] / 2;   // 1,600,000
    char* ws = (char*)d_ws;

    size_t o = 0;
    int*            flags     = (int*)(ws + o);            o += 16;
    int*            cnt       = (int*)(ws + o);            o += 320000;
    int*            cur       = (int*)(ws + o);            o += 320000;
    int*            bucketCur = (int*)(ws + o);            o += 320 * 4;
    unsigned short* Wbf       = (unsigned short*)(ws + o); o += 2 * 24576 * 2;
    float*          bfp       = (float*)(ws + o);          o += 2 * 384 * 4;
    XT* xc  = (XT*)(ws + o); o += (size_t)N_NODES * 128 * sizeof(XT);
    XT* agg = (XT*)(ws + o); o += (size_t)N_NODES * 128 * sizeof(XT);
    unsigned int* recs = (unsigned int*)(ws + o); o += (size_t)NB * CAP * 4;
    int* csr = (int*)(ws + o);                     o += (size_t)NB * CAP * 4;
    // optional bf16 id pack (10.24 MB) — only if workspace allows
    unsigned short* idbf = nullptr;
    int useIdbf = 0;
    if (o + (size_t)N_NODES * DIM * 2 <= ws_size) {
        idbf = (unsigned short*)(ws + o);
        useIdbf = 1;
    }

    detect_kernel<<<dim3(1), dim3(64), 0, stream>>>(
        (const unsigned int*)v_feat, (const int*)ei, flags, bucketCur);

    // edges -> fixed-cap bucket records
    const int binBlocks = (E + 2047) / 2048;          // 782
    binplace_kernel<<<dim3(binBlocks), dim3(256), 0, stream>>>(
        ei, E, flags, bucketCur, recs);

    // bin2csr (313 blocks, overlapped) + init_x + W/b/id pack
    const int initBlocks = (N_NODES + 7) / 8;         // 10000
    const int packElems  = 2 * 24576 + 2 * 384 + (useIdbf ? N_NODES * DIM : 0);
    const int packBlocks = (packElems + 511) / 512;
    prep2_kernel<<<dim3(NB + initBlocks + packBlocks), dim3(512), 0, stream>>>(
        recs, bucketCur, cnt, cur, csr,
        initBlocks, flags,
        v_pref, t_pref, v_feat, t_feat, xc,
        v_W, t_W, v_b, t_b, Wbf, bfp,
        id_emb, idbf, useIdbf);

    const int gatherBlocks = (N_NODES + 7) / 8;       // 10000
    const int denseBlocks  = N_NODES / (16 * 4);      // 1250, exact

    // layer 0 (in-place xc update), layer 1 (writes averaged output directly)
    gather_kernel<<<dim3(gatherBlocks), dim3(512), 0, stream>>>(xc, agg, cnt, cur, csr);
    dense_mfma_kernel<<<dim3(denseBlocks), dim3(256), 0, stream>>>(
        xc, agg, d_out, 0, id_emb, idbf, Wbf, bfp, 0, flags);
    gather_kernel<<<dim3(gatherBlocks), dim3(512), 0, stream>>>(xc, agg, cnt, cur, csr);
    dense_mfma_kernel<<<dim3(denseBlocks), dim3(256), 0, stream>>>(
        xc, agg, d_out, 1, id_emb, idbf, Wbf, bfp, 1, flags);
}

// Round 9
// 365.522 us; speedup vs baseline: 1.2542x; 1.0430x over previous
//
#include <hip/hip_runtime.h>
#include <hip/hip_bf16.h>

#define NUM_USER 50000
#define N_NODES  80000
#define DIM      64
#define NEG_SLOPE 0.01f

// bucket geometry: 256 rows per bucket, fixed capacity (no count pass)
#define NB 313               // ceil(80000/256)
#define BSHIFT 8
#define RMASK 255
#define CSHIFT 17
#define CMASK 0x1FFFF
#define CAP 10240            // item buckets ~6.8K +- 81 -> ~42 sigma margin

typedef __attribute__((ext_vector_type(8))) short short8;   // 8 bf16 = 4 VGPRs
typedef __attribute__((ext_vector_type(4))) float f32x4;    // MFMA 16x16 accumulator

typedef unsigned short XT;   // state dtype: bf16

__device__ __forceinline__ float leaky(float v) {
    return v > 0.0f ? v : v * NEG_SLOPE;
}

// flags[0]: edge_index is int64 (else int32)
// flags[1]: float inputs are bf16 (else fp32)
__device__ __forceinline__ int load_idx(const void* ei, int is64, long long pos) {
    if (is64) return (int)((const long long*)ei)[pos];
    return ((const int*)ei)[pos];
}
__device__ __forceinline__ float load_f(const void* p, int isbf16, size_t i) {
    if (isbf16) return __bfloat162float(((const __hip_bfloat16*)p)[i]);
    return ((const float*)p)[i];
}

__device__ __forceinline__ unsigned short f2bf(float f) {
    unsigned u = __float_as_uint(f);
    u += 0x7fffu + ((u >> 16) & 1u);   // RNE
    return (unsigned short)(u >> 16);
}

__device__ __forceinline__ void acc8(float* a, uint4 r) {
    a[0] += __uint_as_float(r.x << 16);
    a[1] += __uint_as_float(r.x & 0xffff0000u);
    a[2] += __uint_as_float(r.y << 16);
    a[3] += __uint_as_float(r.y & 0xffff0000u);
    a[4] += __uint_as_float(r.z << 16);
    a[5] += __uint_as_float(r.z & 0xffff0000u);
    a[6] += __uint_as_float(r.w << 16);
    a[7] += __uint_as_float(r.w & 0xffff0000u);
}

// ---------- detect (wave-parallel) + zero bucket cursors ----------
__global__ void detect_kernel(const unsigned int* __restrict__ feat_words,
                              const int* __restrict__ ei_words,
                              int* __restrict__ flags,
                              int* __restrict__ bucketCur) {
    int lane = threadIdx.x & 63;
    for (int i = lane; i < 320; i += 64) bucketCur[i] = 0;
    int orv = 0;
    for (int i = lane * 2 + 1; i < 1024; i += 128) orv |= ei_words[i];
    int hits = 0;
    for (int i = lane; i < 256; i += 64) {
        unsigned e = (feat_words[i] >> 7) & 0xFF;
        hits += (e == 126 || e == 127) ? 1 : 0;
    }
    #pragma unroll
    for (int d = 32; d > 0; d >>= 1) {
        orv  |= __shfl_xor(orv, d, 64);
        hits += __shfl_xor(hits, d, 64);
    }
    if (lane == 0 && blockIdx.x == 0) {
        flags[0] = (orv == 0) ? 1 : 0;
        flags[1] = (hits > 64) ? 1 : 0;
    }
}

// ---------- megafuse: binplace + init_x + W/b pack (three block ranges, R6) ----------
__global__ __launch_bounds__(256) void megafuse_kernel(
        const void* __restrict__ ei, int E, int binBlocks, int initBlocks,
        const int* __restrict__ flags,
        int* __restrict__ bucketCur, unsigned int* __restrict__ recs,
        const void* __restrict__ vp, const void* __restrict__ tp,
        const void* __restrict__ vf, const void* __restrict__ tf,
        XT* __restrict__ xc,
        const void* __restrict__ vW, const void* __restrict__ tW,
        const void* __restrict__ vb, const void* __restrict__ tb,
        unsigned short* __restrict__ Wbf, float* __restrict__ bfp) {
    if ((int)blockIdx.x < binBlocks) {
        // ---- edges -> fixed-cap bucket records (block-aggregated cursors)
        __shared__ int bloc[320];
        __shared__ int bres[320];
        int tid = threadIdx.x;
        for (int i = tid; i < 320; i += 256) bloc[i] = 0;
        __syncthreads();
        int is64 = flags[0];
        long long base = (long long)blockIdx.x * 2048;
        int bb[8], cc[8], lp[8], rl[8];
        #pragma unroll
        for (int it = 0; it < 8; ++it) {
            bb[it] = -1;
            long long e = base + it * 256 + tid;
            if (e < E) {
                int r = load_idx(ei, is64, e);
                int c = load_idx(ei, is64, (long long)E + e);
                if ((unsigned)r < N_NODES && (unsigned)c < N_NODES) {
                    int b = r >> BSHIFT;
                    bb[it] = b;
                    cc[it] = c;
                    rl[it] = r & RMASK;
                    lp[it] = atomicAdd(&bloc[b], 1);
                }
            }
        }
        __syncthreads();
        for (int i = tid; i < NB; i += 256) {
            int v = bloc[i];
            bres[i] = v ? atomicAdd(&bucketCur[i], v) : 0;
        }
        __syncthreads();
        #pragma unroll
        for (int it = 0; it < 8; ++it) {
            if (bb[it] >= 0) {
                int pos = bres[bb[it]] + lp[it];
                if (pos < CAP)
                    recs[(size_t)bb[it] * CAP + pos] =
                        ((unsigned)rl[it] << CSHIFT) | (unsigned)cc[it];
            }
        }
    } else if ((int)blockIdx.x < binBlocks + initBlocks) {
        // ---- init_x: L2-normalize [pref|feat] rows -> bf16 state
        int n = (blockIdx.x - binBlocks) * 4 + (threadIdx.x >> 6);
        if (n >= N_NODES) return;
        int lane = threadIdx.x & 63;
        int isb = flags[1];
        float a, b;
        if (n < NUM_USER) {
            a = load_f(vp, isb, (size_t)n * DIM + lane);
            b = load_f(tp, isb, (size_t)n * DIM + lane);
        } else {
            a = load_f(vf, isb, (size_t)(n - NUM_USER) * DIM + lane);
            b = load_f(tf, isb, (size_t)(n - NUM_USER) * DIM + lane);
        }
        float sa = a * a, sb = b * b;
        #pragma unroll
        for (int d = 32; d > 0; d >>= 1) {
            sa += __shfl_xor(sa, d, 64);
            sb += __shfl_xor(sb, d, 64);
        }
        float ra = 1.0f / fmaxf(sqrtf(sa), 1e-12f);
        float rb = 1.0f / fmaxf(sqrtf(sb), 1e-12f);
        xc[(size_t)n * 128 + lane]      = f2bf(a * ra);
        xc[(size_t)n * 128 + 64 + lane] = f2bf(b * rb);
    } else {
        // ---- W/b pack
        int isb = flags[1];
        int j = (blockIdx.x - binBlocks - initBlocks) * 256 + threadIdx.x;
        if (j < 2 * 24576) {
            int tw = j / 24576, r = j % 24576;
            Wbf[j] = f2bf(load_f(tw ? tW : vW, isb, r));
        } else if (j < 2 * 24576 + 2 * 384) {
            int i2 = j - 2 * 24576;
            int tw = i2 / 384, r = i2 % 384;
            bfp[i2] = load_f(tw ? tb : vb, isb, r);
        }
    }
}

// ---------- bin2csr: one block per bucket, 1024 threads (R6) ----------
__global__ __launch_bounds__(1024) void bin2csr_kernel(
        const unsigned int* __restrict__ recs,
        const int* __restrict__ bucketCur,
        int* __restrict__ cnt, int* __restrict__ cur,
        int* __restrict__ csr) {
    __shared__ int rcnt[256];
    __shared__ int sc[256];
    __shared__ int lcur[256];
    int b = blockIdx.x;
    int t = threadIdx.x;
    int base = b * CAP;
    int count = bucketCur[b];
    if (count > CAP) count = CAP;

    if (t < 256) { rcnt[t] = 0; lcur[t] = 0; }
    __syncthreads();
    for (int i = t; i < count; i += 1024) {
        unsigned rec = recs[(size_t)base + i];
        atomicAdd(&rcnt[rec >> CSHIFT], 1);
    }
    __syncthreads();
    int v = (t < 256) ? rcnt[t] : 0;
    if (t < 256) sc[t] = v;
    __syncthreads();
    for (int d = 1; d < 256; d <<= 1) {
        int x = 0;
        if (t < 256) { x = sc[t]; if (t >= d) x += sc[t - d]; }
        __syncthreads();
        if (t < 256) sc[t] = x;
        __syncthreads();
    }
    if (t < 256) {
        int row = (b << BSHIFT) + t;
        if (row < N_NODES) {
            cnt[row] = v;
            cur[row] = base + sc[t];   // row end; gather recovers start = cur - cnt
        }
    }
    __syncthreads();
    for (int i = t; i < count; i += 1024) {
        unsigned rec = recs[(size_t)base + i];
        int rloc = rec >> CSHIFT;
        int c = rec & CMASK;
        int pos = base + (sc[rloc] - rcnt[rloc]) + atomicAdd(&lcur[rloc], 1);
        csr[pos] = c;
    }
}

// ---------- gather: agg[n] = mean over CSR neighbors (proven R3/R6 shape) ----------
__global__ __launch_bounds__(512) void gather_kernel(
        const XT* __restrict__ xc, XT* __restrict__ agg,
        const int* __restrict__ cnt, const int* __restrict__ cur,
        const int* __restrict__ csr) {
    int n = blockIdx.x * 8 + (threadIdx.x >> 6);
    if (n >= N_NODES) return;
    int lane = threadIdx.x & 63;
    int g8 = lane >> 3;      // 0..7
    int s  = lane & 7;       // 0..7
    int gg = g8 >> 1;        // 0..3: neighbor stride class
    int h  = g8 & 1;         // 0/1: row half

    int d = cnt[n];
    int base = cur[n] - d;   // row start in padded CSR
    const int* nb = csr + base;
    const XT* xh = xc + h * 64;

    float acc[8];
    #pragma unroll
    for (int f = 0; f < 8; ++f) acc[f] = 0.f;

    int jj = gg;
    for (; jj + 4 < d; jj += 8) {
        int c0 = nb[jj];
        int c1 = nb[jj + 4];
        uint4 r0 = ((const uint4*)(xh + (size_t)c0 * 128))[s];
        uint4 r1 = ((const uint4*)(xh + (size_t)c1 * 128))[s];
        acc8(acc, r0);
        acc8(acc, r1);
    }
    if (jj < d) {
        int c0 = nb[jj];
        uint4 r0 = ((const uint4*)(xh + (size_t)c0 * 128))[s];
        acc8(acc, r0);
    }

    // reduce across gg (lanes differing in bits 4 and 5; same h,s)
    #pragma unroll
    for (int dd = 16; dd < 64; dd <<= 1) {
        #pragma unroll
        for (int f = 0; f < 8; ++f) acc[f] += __shfl_xor(acc[f], dd, 64);
    }

    float invd = (d > 0) ? 1.0f / (float)d : 0.0f;
    if (g8 < 2) {   // gg == 0 lanes; h = g8 selects the half to write
        uint4 w;
        w.x = (unsigned)f2bf(acc[0] * invd) | ((unsigned)f2bf(acc[1] * invd) << 16);
        w.y = (unsigned)f2bf(acc[2] * invd) | ((unsigned)f2bf(acc[3] * invd) << 16);
        w.z = (unsigned)f2bf(acc[4] * invd) | ((unsigned)f2bf(acc[5] * invd) << 16);
        w.w = (unsigned)f2bf(acc[6] * invd) | ((unsigned)f2bf(acc[7] * invd) << 16);
        ((uint4*)(agg + (size_t)n * 128 + h * 64))[s] = w;
    }
}

// ---------- dense v2: one wave per (16-node tile, tower) ----------
// Halves the per-wave dependency chain and doubles resident waves (grid 2500
// x 4 waves = 10000 waves vs 5000). agg+xc fragment loads hoisted together;
// id loads issued before the LDS ht read so they hide under M0. Tower waves
// touch disjoint 64-col halves of xc -> in-place safe, no barrier (non-last).
// last=1: tower-1 waves stage results in padded LDS, one barrier, tower-0
// waves average + store to out.
__global__ __launch_bounds__(256) void dense_mfma_kernel(
        XT* __restrict__ xc, const XT* __restrict__ agg,
        void* __restrict__ out, int last,
        const void* __restrict__ id_emb,
        const unsigned short* __restrict__ Wbf, const float* __restrict__ bfp,
        int layer, const int* __restrict__ flags) {
    __shared__ unsigned short hts[4][16 * 72];   // 9216 B
    __shared__ float res[2][16][65];             // 8320 B (last-layer staging)
    int wave = threadIdx.x >> 6, lane = threadIdx.x & 63;
    int quad = lane >> 4, l16 = lane & 15;
    int tile  = wave >> 1;   // 0..1
    int tower = wave & 1;    // 0..1
    int isb = flags[1];
    int n0 = (blockIdx.x * 2 + tile) * 16;
    int toff = tower * 64;
    const unsigned short* Wm = Wbf + (size_t)((tower * 2 + layer) * 3) * 4096;
    const float* bb = bfp + (tower * 2 + layer) * 192;
    unsigned short* ht = hts[wave];

    size_t arow = (size_t)(n0 + l16) * 128 + toff + quad * 8;

    // hoisted: both A-fragment pairs in flight together
    short8 x0  = *(const short8*)(xc + arow);
    short8 x1  = *(const short8*)(xc + arow + 32);
    short8 ga0 = *(const short8*)(agg + arow);
    short8 ga1 = *(const short8*)(agg + arow + 32);

    f32x4 accP[4];

    // M1: P = leaky(x @ W1^T + b1), in registers
    #pragma unroll
    for (int t = 0; t < 4; ++t) {
        f32x4 c = {0.f, 0.f, 0.f, 0.f};
        short8 b0 = *(const short8*)(Wm + 4096 + (16 * t + l16) * 64 + quad * 8);
        short8 b1 = *(const short8*)(Wm + 4096 + (16 * t + l16) * 64 + 32 + quad * 8);
        c = __builtin_amdgcn_mfma_f32_16x16x32_bf16(x0, b0, c, 0, 0, 0);
        c = __builtin_amdgcn_mfma_f32_16x16x32_bf16(x1, b1, c, 0, 0, 0);
        float bias = bb[64 + 16 * t + l16];
        #pragma unroll
        for (int r = 0; r < 4; ++r) accP[t][r] = leaky(c[r] + bias);
    }

    // M0: h = leaky(agg @ W0^T + b0) -> LDS (C-layout -> A-layout)
    #pragma unroll
    for (int t = 0; t < 4; ++t) {
        f32x4 c = {0.f, 0.f, 0.f, 0.f};
        short8 b0 = *(const short8*)(Wm + (16 * t + l16) * 64 + quad * 8);
        short8 b1 = *(const short8*)(Wm + (16 * t + l16) * 64 + 32 + quad * 8);
        c = __builtin_amdgcn_mfma_f32_16x16x32_bf16(ga0, b0, c, 0, 0, 0);
        c = __builtin_amdgcn_mfma_f32_16x16x32_bf16(ga1, b1, c, 0, 0, 0);
        float bias = bb[16 * t + l16];
        #pragma unroll
        for (int r = 0; r < 4; ++r)
            ht[(quad * 4 + r) * 72 + 16 * t + l16] = f2bf(leaky(c[r] + bias));
    }

    // id values (issued here; latency hides under the ht read + M2 weights)
    float idv[16];
    #pragma unroll
    for (int t = 0; t < 4; ++t)
        #pragma unroll
        for (int r = 0; r < 4; ++r)
            idv[t * 4 + r] = load_f(id_emb, isb,
                                    (size_t)(n0 + quad * 4 + r) * 64 + 16 * t + l16);

    // wave-private LDS, in-order per wave -> no barrier before read
    short8 a0 = *(const short8*)(ht + l16 * 72 + quad * 8);
    short8 a1 = *(const short8*)(ht + l16 * 72 + 32 + quad * 8);

    // M2: x = leaky(h @ W2^T + b2 + P + id)
    float xres[16];
    #pragma unroll
    for (int t = 0; t < 4; ++t) {
        f32x4 c = {0.f, 0.f, 0.f, 0.f};
        short8 b0 = *(const short8*)(Wm + 2 * 4096 + (16 * t + l16) * 64 + quad * 8);
        short8 b1 = *(const short8*)(Wm + 2 * 4096 + (16 * t + l16) * 64 + 32 + quad * 8);
        c = __builtin_amdgcn_mfma_f32_16x16x32_bf16(a0, b0, c, 0, 0, 0);
        c = __builtin_amdgcn_mfma_f32_16x16x32_bf16(a1, b1, c, 0, 0, 0);
        float bias = bb[128 + 16 * t + l16];
        #pragma unroll
        for (int r = 0; r < 4; ++r)
            xres[t * 4 + r] = leaky(c[r] + bias + accP[t][r] + idv[t * 4 + r]);
    }

    if (!last) {
        #pragma unroll
        for (int t = 0; t < 4; ++t) {
            #pragma unroll
            for (int r = 0; r < 4; ++r) {
                int node2 = n0 + quad * 4 + r;
                int j = 16 * t + l16;
                xc[(size_t)node2 * 128 + toff + j] = f2bf(xres[t * 4 + r]);
            }
        }
    } else {
        if (tower == 1) {
            #pragma unroll
            for (int t = 0; t < 4; ++t)
                #pragma unroll
                for (int r = 0; r < 4; ++r)
                    res[tile][quad * 4 + r][16 * t + l16] = xres[t * 4 + r];
        }
        __syncthreads();
        if (tower == 0) {
            #pragma unroll
            for (int t = 0; t < 4; ++t) {
                #pragma unroll
                for (int r = 0; r < 4; ++r) {
                    int node2 = n0 + quad * 4 + r;
                    int j = 16 * t + l16;
                    float avg = (xres[t * 4 + r] + res[tile][quad * 4 + r][j]) * 0.5f;
                    if (isb) ((unsigned short*)out)[(size_t)node2 * 64 + j] = f2bf(avg);
                    else     ((float*)out)[(size_t)node2 * 64 + j] = avg;
                }
            }
        }
    }
}

extern "C" void kernel_launch(void* const* d_in, const int* in_sizes, int n_in,
                              void* d_out, int out_size, void* d_ws, size_t ws_size,
                              hipStream_t stream) {
    const void* v_feat = d_in[0];
    const void* t_feat = d_in[1];
    const void* id_emb = d_in[2];
    const void* v_pref = d_in[3];
    const void* t_pref = d_in[4];
    const void* v_W    = d_in[5];
    const void* v_b    = d_in[6];
    const void* t_W    = d_in[7];
    const void* t_b    = d_in[8];
    const void* ei     = d_in[9];

    const int E = in_sizes[9] / 2;   // 1,600,000
    char* ws = (char*)d_ws;

    size_t o = 0;
    int*            flags     = (int*)(ws + o);            o += 16;
    int*            cnt       = (int*)(ws + o);            o += 320000;
    int*            cur       = (int*)(ws + o);            o += 320000;
    int*            bucketCur = (int*)(ws + o);            o += 320 * 4;
    unsigned short* Wbf       = (unsigned short*)(ws + o); o += 2 * 24576 * 2;
    float*          bfp       = (float*)(ws + o);          o += 2 * 384 * 4;
    XT* xc  = (XT*)(ws + o); o += (size_t)N_NODES * 128 * sizeof(XT);
    XT* agg = (XT*)(ws + o); o += (size_t)N_NODES * 128 * sizeof(XT);
    unsigned int* recs = (unsigned int*)(ws + o); o += (size_t)NB * CAP * 4;
    int* csr = (int*)(ws + o);                    // padded: NB*CAP*4 = 12.8 MB

    detect_kernel<<<dim3(1), dim3(64), 0, stream>>>(
        (const unsigned int*)v_feat, (const int*)ei, flags, bucketCur);

    // fused binplace + init_x + W/b pack (R6 structure)
    const int binBlocks  = (E + 2047) / 2048;         // 782
    const int initBlocks = (N_NODES + 3) / 4;         // 20000
    const int packBlocks = (2 * 24576 + 2 * 384 + 255) / 256;
    megafuse_kernel<<<dim3(binBlocks + initBlocks + packBlocks), dim3(256), 0, stream>>>(
        ei, E, binBlocks, initBlocks, flags, bucketCur, recs,
        v_pref, t_pref, v_feat, t_feat, xc,
        v_W, t_W, v_b, t_b, Wbf, bfp);

    // buckets -> padded CSR + per-row cnt/cur
    bin2csr_kernel<<<dim3(NB), dim3(1024), 0, stream>>>(recs, bucketCur, cnt, cur, csr);

    const int gatherBlocks = (N_NODES + 7) / 8;       // 10000
    const int denseBlocks  = N_NODES / 32;            // 2500, exact

    // layer 0 (in-place xc update), layer 1 (writes averaged output directly)
    gather_kernel<<<dim3(gatherBlocks), dim3(512), 0, stream>>>(xc, agg, cnt, cur, csr);
    dense_mfma_kernel<<<dim3(denseBlocks), dim3(256), 0, stream>>>(
        xc, agg, d_out, 0, id_emb, Wbf, bfp, 0, flags);
    gather_kernel<<<dim3(gatherBlocks), dim3(512), 0, stream>>>(xc, agg, cnt, cur, csr);
    dense_mfma_kernel<<<dim3(denseBlocks), dim3(256), 0, stream>>>(
        xc, agg, d_out, 1, id_emb, Wbf, bfp, 1, flags);
}

// Round 10
// 344.058 us; speedup vs baseline: 1.3324x; 1.0624x over previous
//
#include <hip/hip_runtime.h>
#include <hip/hip_bf16.h>

#define NUM_USER 50000
#define N_NODES  80000
#define DIM      64
#define NEG_SLOPE 0.01f

// bucket geometry: 256 rows per bucket, fixed capacity (no count pass)
#define NB 313               // ceil(80000/256)
#define BSHIFT 8
#define RMASK 255
#define CSHIFT 17
#define CMASK 0x1FFFF
#define CAP 10240            // item buckets ~6.8K +- 81 -> ~42 sigma margin

typedef __attribute__((ext_vector_type(8))) short short8;   // 8 bf16 = 4 VGPRs
typedef __attribute__((ext_vector_type(4))) float f32x4;    // MFMA 16x16 accumulator

typedef unsigned short XT;   // state dtype: bf16

__device__ __forceinline__ float leaky(float v) {
    return v > 0.0f ? v : v * NEG_SLOPE;
}

// flags[0]: edge_index is int64 (else int32)
// flags[1]: float inputs are bf16 (else fp32)
__device__ __forceinline__ int load_idx(const void* ei, int is64, long long pos) {
    if (is64) return (int)((const long long*)ei)[pos];
    return ((const int*)ei)[pos];
}
__device__ __forceinline__ float load_f(const void* p, int isbf16, size_t i) {
    if (isbf16) return __bfloat162float(((const __hip_bfloat16*)p)[i]);
    return ((const float*)p)[i];
}

__device__ __forceinline__ unsigned short f2bf(float f) {
    unsigned u = __float_as_uint(f);
    u += 0x7fffu + ((u >> 16) & 1u);   // RNE
    return (unsigned short)(u >> 16);
}

__device__ __forceinline__ void acc8(float* a, uint4 r) {
    a[0] += __uint_as_float(r.x << 16);
    a[1] += __uint_as_float(r.x & 0xffff0000u);
    a[2] += __uint_as_float(r.y << 16);
    a[3] += __uint_as_float(r.y & 0xffff0000u);
    a[4] += __uint_as_float(r.z << 16);
    a[5] += __uint_as_float(r.z & 0xffff0000u);
    a[6] += __uint_as_float(r.w << 16);
    a[7] += __uint_as_float(r.w & 0xffff0000u);
}

// ---------- detect (wave-parallel) + zero bucket cursors ----------
__global__ void detect_kernel(const unsigned int* __restrict__ feat_words,
                              const int* __restrict__ ei_words,
                              int* __restrict__ flags,
                              int* __restrict__ bucketCur) {
    int lane = threadIdx.x & 63;
    for (int i = lane; i < 320; i += 64) bucketCur[i] = 0;
    int orv = 0;
    for (int i = lane * 2 + 1; i < 1024; i += 128) orv |= ei_words[i];
    int hits = 0;
    for (int i = lane; i < 256; i += 64) {
        unsigned e = (feat_words[i] >> 7) & 0xFF;
        hits += (e == 126 || e == 127) ? 1 : 0;
    }
    #pragma unroll
    for (int d = 32; d > 0; d >>= 1) {
        orv  |= __shfl_xor(orv, d, 64);
        hits += __shfl_xor(hits, d, 64);
    }
    if (lane == 0 && blockIdx.x == 0) {
        flags[0] = (orv == 0) ? 1 : 0;
        flags[1] = (hits > 64) ? 1 : 0;
    }
}

// ---------- megafuse: binplace + init_x + W/b pack (three block ranges, R6) ----------
__global__ __launch_bounds__(256) void megafuse_kernel(
        const void* __restrict__ ei, int E, int binBlocks, int initBlocks,
        const int* __restrict__ flags,
        int* __restrict__ bucketCur, unsigned int* __restrict__ recs,
        const void* __restrict__ vp, const void* __restrict__ tp,
        const void* __restrict__ vf, const void* __restrict__ tf,
        XT* __restrict__ xc,
        const void* __restrict__ vW, const void* __restrict__ tW,
        const void* __restrict__ vb, const void* __restrict__ tb,
        unsigned short* __restrict__ Wbf, float* __restrict__ bfp) {
    if ((int)blockIdx.x < binBlocks) {
        // ---- edges -> fixed-cap bucket records (block-aggregated cursors)
        __shared__ int bloc[320];
        __shared__ int bres[320];
        int tid = threadIdx.x;
        for (int i = tid; i < 320; i += 256) bloc[i] = 0;
        __syncthreads();
        int is64 = flags[0];
        long long base = (long long)blockIdx.x * 2048;
        int bb[8], cc[8], lp[8], rl[8];
        #pragma unroll
        for (int it = 0; it < 8; ++it) {
            bb[it] = -1;
            long long e = base + it * 256 + tid;
            if (e < E) {
                int r = load_idx(ei, is64, e);
                int c = load_idx(ei, is64, (long long)E + e);
                if ((unsigned)r < N_NODES && (unsigned)c < N_NODES) {
                    int b = r >> BSHIFT;
                    bb[it] = b;
                    cc[it] = c;
                    rl[it] = r & RMASK;
                    lp[it] = atomicAdd(&bloc[b], 1);
                }
            }
        }
        __syncthreads();
        for (int i = tid; i < NB; i += 256) {
            int v = bloc[i];
            bres[i] = v ? atomicAdd(&bucketCur[i], v) : 0;
        }
        __syncthreads();
        #pragma unroll
        for (int it = 0; it < 8; ++it) {
            if (bb[it] >= 0) {
                int pos = bres[bb[it]] + lp[it];
                if (pos < CAP)
                    recs[(size_t)bb[it] * CAP + pos] =
                        ((unsigned)rl[it] << CSHIFT) | (unsigned)cc[it];
            }
        }
    } else if ((int)blockIdx.x < binBlocks + initBlocks) {
        // ---- init_x: L2-normalize [pref|feat] rows -> bf16 state
        int n = (blockIdx.x - binBlocks) * 4 + (threadIdx.x >> 6);
        if (n >= N_NODES) return;
        int lane = threadIdx.x & 63;
        int isb = flags[1];
        float a, b;
        if (n < NUM_USER) {
            a = load_f(vp, isb, (size_t)n * DIM + lane);
            b = load_f(tp, isb, (size_t)n * DIM + lane);
        } else {
            a = load_f(vf, isb, (size_t)(n - NUM_USER) * DIM + lane);
            b = load_f(tf, isb, (size_t)(n - NUM_USER) * DIM + lane);
        }
        float sa = a * a, sb = b * b;
        #pragma unroll
        for (int d = 32; d > 0; d >>= 1) {
            sa += __shfl_xor(sa, d, 64);
            sb += __shfl_xor(sb, d, 64);
        }
        float ra = 1.0f / fmaxf(sqrtf(sa), 1e-12f);
        float rb = 1.0f / fmaxf(sqrtf(sb), 1e-12f);
        xc[(size_t)n * 128 + lane]      = f2bf(a * ra);
        xc[(size_t)n * 128 + 64 + lane] = f2bf(b * rb);
    } else {
        // ---- W/b pack
        int isb = flags[1];
        int j = (blockIdx.x - binBlocks - initBlocks) * 256 + threadIdx.x;
        if (j < 2 * 24576) {
            int tw = j / 24576, r = j % 24576;
            Wbf[j] = f2bf(load_f(tw ? tW : vW, isb, r));
        } else if (j < 2 * 24576 + 2 * 384) {
            int i2 = j - 2 * 24576;
            int tw = i2 / 384, r = i2 % 384;
            bfp[i2] = load_f(tw ? tb : vb, isb, r);
        }
    }
}

// ---------- bin2csr: one block per bucket, 1024 threads (R6) ----------
__global__ __launch_bounds__(1024) void bin2csr_kernel(
        const unsigned int* __restrict__ recs,
        const int* __restrict__ bucketCur,
        int* __restrict__ cnt, int* __restrict__ cur,
        int* __restrict__ csr) {
    __shared__ int rcnt[256];
    __shared__ int sc[256];
    __shared__ int lcur[256];
    int b = blockIdx.x;
    int t = threadIdx.x;
    int base = b * CAP;
    int count = bucketCur[b];
    if (count > CAP) count = CAP;

    if (t < 256) { rcnt[t] = 0; lcur[t] = 0; }
    __syncthreads();
    for (int i = t; i < count; i += 1024) {
        unsigned rec = recs[(size_t)base + i];
        atomicAdd(&rcnt[rec >> CSHIFT], 1);
    }
    __syncthreads();
    int v = (t < 256) ? rcnt[t] : 0;
    if (t < 256) sc[t] = v;
    __syncthreads();
    for (int d = 1; d < 256; d <<= 1) {
        int x = 0;
        if (t < 256) { x = sc[t]; if (t >= d) x += sc[t - d]; }
        __syncthreads();
        if (t < 256) sc[t] = x;
        __syncthreads();
    }
    if (t < 256) {
        int row = (b << BSHIFT) + t;
        if (row < N_NODES) {
            cnt[row] = v;
            cur[row] = base + sc[t];   // row end; gather recovers start = cur - cnt
        }
    }
    __syncthreads();
    for (int i = t; i < count; i += 1024) {
        unsigned rec = recs[(size_t)base + i];
        int rloc = rec >> CSHIFT;
        int c = rec & CMASK;
        int pos = base + (sc[rloc] - rcnt[rloc]) + atomicAdd(&lcur[rloc], 1);
        csr[pos] = c;
    }
}

// ---------- gather: agg[n] = mean over CSR neighbors (proven R3/R6 shape) ----------
__global__ __launch_bounds__(512) void gather_kernel(
        const XT* __restrict__ xc, XT* __restrict__ agg,
        const int* __restrict__ cnt, const int* __restrict__ cur,
        const int* __restrict__ csr) {
    int n = blockIdx.x * 8 + (threadIdx.x >> 6);
    if (n >= N_NODES) return;
    int lane = threadIdx.x & 63;
    int g8 = lane >> 3;      // 0..7
    int s  = lane & 7;       // 0..7
    int gg = g8 >> 1;        // 0..3: neighbor stride class
    int h  = g8 & 1;         // 0/1: row half

    int d = cnt[n];
    int base = cur[n] - d;   // row start in padded CSR
    const int* nb = csr + base;
    const XT* xh = xc + h * 64;

    float acc[8];
    #pragma unroll
    for (int f = 0; f < 8; ++f) acc[f] = 0.f;

    int jj = gg;
    for (; jj + 4 < d; jj += 8) {
        int c0 = nb[jj];
        int c1 = nb[jj + 4];
        uint4 r0 = ((const uint4*)(xh + (size_t)c0 * 128))[s];
        uint4 r1 = ((const uint4*)(xh + (size_t)c1 * 128))[s];
        acc8(acc, r0);
        acc8(acc, r1);
    }
    if (jj < d) {
        int c0 = nb[jj];
        uint4 r0 = ((const uint4*)(xh + (size_t)c0 * 128))[s];
        acc8(acc, r0);
    }

    // reduce across gg (lanes differing in bits 4 and 5; same h,s)
    #pragma unroll
    for (int dd = 16; dd < 64; dd <<= 1) {
        #pragma unroll
        for (int f = 0; f < 8; ++f) acc[f] += __shfl_xor(acc[f], dd, 64);
    }

    float invd = (d > 0) ? 1.0f / (float)d : 0.0f;
    if (g8 < 2) {   // gg == 0 lanes; h = g8 selects the half to write
        uint4 w;
        w.x = (unsigned)f2bf(acc[0] * invd) | ((unsigned)f2bf(acc[1] * invd) << 16);
        w.y = (unsigned)f2bf(acc[2] * invd) | ((unsigned)f2bf(acc[3] * invd) << 16);
        w.z = (unsigned)f2bf(acc[4] * invd) | ((unsigned)f2bf(acc[5] * invd) << 16);
        w.w = (unsigned)f2bf(acc[6] * invd) | ((unsigned)f2bf(acc[7] * invd) << 16);
        ((uint4*)(agg + (size_t)n * 128 + h * 64))[s] = w;
    }
}

// ---------- dense v3: W staged in LDS; 512 thr = 8 tiles, one tower/block ----------
// W per (tower,layer) = 24KB, loaded once per block into LDS with row stride
// 72 shorts (quarter-wave fragment reads -> 2-way banks = free). Removes the
// 24 strided global W loads per wave (L1 thrash on the MFMA chain) that kept
// dense latency-bound regardless of occupancy (R9 null). Always writes xc
// (in-place safe: blocks write only their own rows' tower half); final_kernel
// does the cross-tower average.
__global__ __launch_bounds__(512) void dense_mfma_kernel(
        XT* __restrict__ xc, const XT* __restrict__ agg,
        const void* __restrict__ id_emb,
        const unsigned short* __restrict__ Wbf, const float* __restrict__ bfp,
        int layer, const int* __restrict__ flags) {
    __shared__ unsigned short Wl[3 * 64 * 72];   // 27648 B
    __shared__ unsigned short hts[8][16 * 72];   // 18432 B
    int tower = blockIdx.y;
    int wave = threadIdx.x >> 6, lane = threadIdx.x & 63;
    int quad = lane >> 4, l16 = lane & 15;
    int isb = flags[1];
    int toff = tower * 64;
    const unsigned short* Wg = Wbf + (size_t)((tower * 2 + layer) * 3) * 4096;
    const float* bb = bfp + (tower * 2 + layer) * 192;
    unsigned short* ht = hts[wave];

    // cooperative W load: 12288 shorts = 1536 uint4, 3 per thread
    for (int i = threadIdx.x; i < 1536; i += 512) {
        int lin = i * 8;
        int mat = lin >> 12;
        int rem = lin & 4095;
        uint4 v = *(const uint4*)(Wg + lin);
        *(uint4*)(Wl + mat * 4608 + (rem >> 6) * 72 + (rem & 63)) = v;
    }
    __syncthreads();

    int n0 = (blockIdx.x * 8 + wave) * 16;
    size_t arow = (size_t)(n0 + l16) * 128 + toff + quad * 8;

    // hoisted A-fragment loads (the only global loads on the chain)
    short8 x0  = *(const short8*)(xc + arow);
    short8 x1  = *(const short8*)(xc + arow + 32);
    short8 ga0 = *(const short8*)(agg + arow);
    short8 ga1 = *(const short8*)(agg + arow + 32);

    f32x4 accP[4];

    // M1: P = leaky(x @ W1^T + b1), in registers
    #pragma unroll
    for (int t = 0; t < 4; ++t) {
        f32x4 c = {0.f, 0.f, 0.f, 0.f};
        short8 b0 = *(const short8*)(Wl + 4608 + (16 * t + l16) * 72 + quad * 8);
        short8 b1 = *(const short8*)(Wl + 4608 + (16 * t + l16) * 72 + 32 + quad * 8);
        c = __builtin_amdgcn_mfma_f32_16x16x32_bf16(x0, b0, c, 0, 0, 0);
        c = __builtin_amdgcn_mfma_f32_16x16x32_bf16(x1, b1, c, 0, 0, 0);
        float bias = bb[64 + 16 * t + l16];
        #pragma unroll
        for (int r = 0; r < 4; ++r) accP[t][r] = leaky(c[r] + bias);
    }

    // M0: h = leaky(agg @ W0^T + b0) -> LDS ht (C-layout -> A-layout)
    #pragma unroll
    for (int t = 0; t < 4; ++t) {
        f32x4 c = {0.f, 0.f, 0.f, 0.f};
        short8 b0 = *(const short8*)(Wl + (16 * t + l16) * 72 + quad * 8);
        short8 b1 = *(const short8*)(Wl + (16 * t + l16) * 72 + 32 + quad * 8);
        c = __builtin_amdgcn_mfma_f32_16x16x32_bf16(ga0, b0, c, 0, 0, 0);
        c = __builtin_amdgcn_mfma_f32_16x16x32_bf16(ga1, b1, c, 0, 0, 0);
        float bias = bb[16 * t + l16];
        #pragma unroll
        for (int r = 0; r < 4; ++r)
            ht[(quad * 4 + r) * 72 + 16 * t + l16] = f2bf(leaky(c[r] + bias));
    }

    // id values: issued here, latency hides under the ht read + M2
    float idv[16];
    #pragma unroll
    for (int t = 0; t < 4; ++t)
        #pragma unroll
        for (int r = 0; r < 4; ++r)
            idv[t * 4 + r] = load_f(id_emb, isb,
                                    (size_t)(n0 + quad * 4 + r) * 64 + 16 * t + l16);

    // wave-private LDS, in-order per wave -> no barrier before read
    short8 a0 = *(const short8*)(ht + l16 * 72 + quad * 8);
    short8 a1 = *(const short8*)(ht + l16 * 72 + 32 + quad * 8);

    // M2: x = leaky(h @ W2^T + b2 + P + id) -> xc (in place)
    #pragma unroll
    for (int t = 0; t < 4; ++t) {
        f32x4 c = {0.f, 0.f, 0.f, 0.f};
        short8 b0 = *(const short8*)(Wl + 2 * 4608 + (16 * t + l16) * 72 + quad * 8);
        short8 b1 = *(const short8*)(Wl + 2 * 4608 + (16 * t + l16) * 72 + 32 + quad * 8);
        c = __builtin_amdgcn_mfma_f32_16x16x32_bf16(a0, b0, c, 0, 0, 0);
        c = __builtin_amdgcn_mfma_f32_16x16x32_bf16(a1, b1, c, 0, 0, 0);
        float bias = bb[128 + 16 * t + l16];
        #pragma unroll
        for (int r = 0; r < 4; ++r) {
            int node2 = n0 + quad * 4 + r;
            int j = 16 * t + l16;
            float v = leaky(c[r] + bias + accP[t][r] + idv[t * 4 + r]);
            xc[(size_t)node2 * 128 + toff + j] = f2bf(v);
        }
    }
}

// ---------- out = (rep_v + rep_t)/2, 8 values/thread ----------
__global__ void final_kernel(const XT* __restrict__ xc, void* __restrict__ out,
                             const int* __restrict__ flags, int n8) {
    int i = blockIdx.x * blockDim.x + threadIdx.x;
    if (i >= n8) return;
    int n = i >> 3, s = i & 7;
    uint4 v = ((const uint4*)(xc + (size_t)n * 128))[s];
    uint4 t = ((const uint4*)(xc + (size_t)n * 128 + 64))[s];
    float r[8];
    r[0] = (__uint_as_float(v.x << 16) + __uint_as_float(t.x << 16)) * 0.5f;
    r[1] = (__uint_as_float(v.x & 0xffff0000u) + __uint_as_float(t.x & 0xffff0000u)) * 0.5f;
    r[2] = (__uint_as_float(v.y << 16) + __uint_as_float(t.y << 16)) * 0.5f;
    r[3] = (__uint_as_float(v.y & 0xffff0000u) + __uint_as_float(t.y & 0xffff0000u)) * 0.5f;
    r[4] = (__uint_as_float(v.z << 16) + __uint_as_float(t.z << 16)) * 0.5f;
    r[5] = (__uint_as_float(v.z & 0xffff0000u) + __uint_as_float(t.z & 0xffff0000u)) * 0.5f;
    r[6] = (__uint_as_float(v.w << 16) + __uint_as_float(t.w << 16)) * 0.5f;
    r[7] = (__uint_as_float(v.w & 0xffff0000u) + __uint_as_float(t.w & 0xffff0000u)) * 0.5f;
    if (flags[1]) {
        uint4 o;
        o.x = (unsigned)f2bf(r[0]) | ((unsigned)f2bf(r[1]) << 16);
        o.y = (unsigned)f2bf(r[2]) | ((unsigned)f2bf(r[3]) << 16);
        o.z = (unsigned)f2bf(r[4]) | ((unsigned)f2bf(r[5]) << 16);
        o.w = (unsigned)f2bf(r[6]) | ((unsigned)f2bf(r[7]) << 16);
        ((uint4*)out)[i] = o;
    } else {
        float4* o = (float4*)out;
        o[i * 2 + 0] = make_float4(r[0], r[1], r[2], r[3]);
        o[i * 2 + 1] = make_float4(r[4], r[5], r[6], r[7]);
    }
}

extern "C" void kernel_launch(void* const* d_in, const int* in_sizes, int n_in,
                              void* d_out, int out_size, void* d_ws, size_t ws_size,
                              hipStream_t stream) {
    const void* v_feat = d_in[0];
    const void* t_feat = d_in[1];
    const void* id_emb = d_in[2];
    const void* v_pref = d_in[3];
    const void* t_pref = d_in[4];
    const void* v_W    = d_in[5];
    const void* v_b    = d_in[6];
    const void* t_W    = d_in[7];
    const void* t_b    = d_in[8];
    const void* ei     = d_in[9];

    const int E = in_sizes[9] / 2;   // 1,600,000
    char* ws = (char*)d_ws;

    size_t o = 0;
    int*            flags     = (int*)(ws + o);            o += 16;
    int*            cnt       = (int*)(ws + o);            o += 320000;
    int*            cur       = (int*)(ws + o);            o += 320000;
    int*            bucketCur = (int*)(ws + o);            o += 320 * 4;
    unsigned short* Wbf       = (unsigned short*)(ws + o); o += 2 * 24576 * 2;
    float*          bfp       = (float*)(ws + o);          o += 2 * 384 * 4;
    XT* xc  = (XT*)(ws + o); o += (size_t)N_NODES * 128 * sizeof(XT);
    XT* agg = (XT*)(ws + o); o += (size_t)N_NODES * 128 * sizeof(XT);
    unsigned int* recs = (unsigned int*)(ws + o); o += (size_t)NB * CAP * 4;
    int* csr = (int*)(ws + o);                    // padded: NB*CAP*4 = 12.8 MB

    detect_kernel<<<dim3(1), dim3(64), 0, stream>>>(
        (const unsigned int*)v_feat, (const int*)ei, flags, bucketCur);

    // fused binplace + init_x + W/b pack
    const int binBlocks  = (E + 2047) / 2048;         // 782
    const int initBlocks = (N_NODES + 3) / 4;         // 20000
    const int packBlocks = (2 * 24576 + 2 * 384 + 255) / 256;
    megafuse_kernel<<<dim3(binBlocks + initBlocks + packBlocks), dim3(256), 0, stream>>>(
        ei, E, binBlocks, initBlocks, flags, bucketCur, recs,
        v_pref, t_pref, v_feat, t_feat, xc,
        v_W, t_W, v_b, t_b, Wbf, bfp);

    // buckets -> padded CSR + per-row cnt/cur
    bin2csr_kernel<<<dim3(NB), dim3(1024), 0, stream>>>(recs, bucketCur, cnt, cur, csr);

    const int gatherBlocks = (N_NODES + 7) / 8;       // 10000
    const int denseBlocksX = N_NODES / (16 * 8);      // 625, exact

    for (int layer = 0; layer < 2; ++layer) {
        gather_kernel<<<dim3(gatherBlocks), dim3(512), 0, stream>>>(xc, agg, cnt, cur, csr);
        dense_mfma_kernel<<<dim3(denseBlocksX, 2), dim3(512), 0, stream>>>(
            xc, agg, id_emb, Wbf, bfp, layer, flags);
    }

    const int n8 = N_NODES * DIM / 8;                 // 640000
    final_kernel<<<dim3((n8 + 255) / 256), dim3(256), 0, stream>>>(xc, d_out, flags, n8);
}